// Round 4
// baseline (202.683 us; speedup 1.0000x reference)
//
#include <hip/hip_runtime.h>

#define OUT_F 11008
#define IN_F  4096
#define PKW   2048   // int32 words per weight row (each word = 1 byte = 2 nibbles)
#define BLKQ  128

typedef __attribute__((ext_vector_type(8))) short          s16x8;
typedef __attribute__((ext_vector_type(8))) unsigned short u16x8;
typedef __attribute__((ext_vector_type(4))) float          f32x4;
typedef __attribute__((ext_vector_type(4))) int            i32x4;

#define STR_(x) #x
#define XSTR(x) STR_(x)

__device__ __forceinline__ unsigned short f2bf(float f) {
    union { float f; unsigned u; } v; v.f = f;
    unsigned r = v.u + 0x8000u + ((v.u >> 16) & 1u);   // RNE-ish
    return (unsigned short)(r >> 16);
}

// Pre-swizzle x (64x4096 f32) into MFMA A-fragment order (bf16):
//   xf[((kb*4 + mt)*64 + lane)*8 + i] = x[mt*16 + (lane&15)][kb*32 + (lane>>4)*8 + i]
__global__ void prep_xfrag(const float* __restrict__ x, unsigned short* __restrict__ xf) {
    int kb   = blockIdx.x;            // 0..127 (k-window of 32)
    int t    = threadIdx.x;           // 0..255
    int mt   = t >> 6;
    int lane = t & 63;
    int m  = mt * 16 + (lane & 15);
    int k0 = kb * 32 + (lane >> 4) * 8;
    const float* xp = x + m * IN_F + k0;
    f32x4 a = *(const f32x4*)(xp);
    f32x4 b = *(const f32x4*)(xp + 4);
    u16x8 v;
    v[0] = f2bf(a[0]); v[1] = f2bf(a[1]); v[2] = f2bf(a[2]); v[3] = f2bf(a[3]);
    v[4] = f2bf(b[0]); v[5] = f2bf(b[1]); v[6] = f2bf(b[2]); v[7] = f2bf(b[3]);
    *(u16x8*)(xf + (size_t)((kb * 4 + mt) * 64 + lane) * 8) = v;
}

// LDS: wave-private 4-slot weight ring (8 waves x 4 x 1KB = 32KB), aliased
// with the epilogue reduction buffer (wave w's lsum slice == wave w's ring).
union SmT {
    unsigned char ring[8][4][1024];
    float         lsum[8192];
};

// Main: one WG (512 thr = 8 waves) per 16 output cols.
// Wave w owns windows {w, w+8, ..., w+120} (16 rounds); window mod 4 == w&3
// is FIXED -> dequant table is 16 VGPRs.  Barrier-free main loop:
//   per round r: issue block(r+3) = [1 global_load_lds W-chunk + 4 A-frag
//   reg loads]  ->  sched_barrier  ->  s_waitcnt vmcnt(15)  (3 blocks x 5
//   ops allowed in flight; uniform distance so the in-order counter never
//   forces a recent op)  ->  ds_read_b128 W  ->  dequant  ->  4 MFMA.
// global_load_lds is side-effecting (can't be sunk, unlike R3's register
// loads -> VGPR_Count=32 JIT collapse); A-frag slots are literal-indexed
// across 16 fully-unrolled rounds (rule #20).  W staging source is
// pre-swizzled (lane -> row=lane&15, quad=lane>>4) so the LDS read-back is
// linear lane*16 and conflict-free (T21).
__global__ __launch_bounds__(512, 4) void qlin_main(
    const int*   __restrict__ wq,
    const float* __restrict__ scale,
    const float* __restrict__ zp,
    const float* __restrict__ bias,
    const unsigned short* __restrict__ xf,
    float* __restrict__ out)
{
    __shared__ SmT sm;

    const int t      = threadIdx.x;
    const int o_base = blockIdx.x * 16;
    const int wave   = t >> 6;        // 0..7
    const int lane   = t & 63;
    const int o_r    = lane & 15;     // output col within tile (B-frag col)
    const int quad   = lane >> 4;     // k-quad within 32-k window
    const int o      = o_base + o_r;

    // dequant constants for FIXED j = (wave&3)*32 + quad*8 + i, i=0..7
    float s[8], zs[8];
    {
        const float* sp  = scale + (size_t)o * BLKQ + (wave & 3) * 32 + quad * 8;
        const float* zpp = zp    + (size_t)o * BLKQ + (wave & 3) * 32 + quad * 8;
        f32x4 s0 = *(const f32x4*)(sp);
        f32x4 s1 = *(const f32x4*)(sp + 4);
        f32x4 z0 = *(const f32x4*)(zpp);
        f32x4 z1 = *(const f32x4*)(zpp + 4);
        #pragma unroll
        for (int i = 0; i < 4; ++i) {
            s [i]     = s0[i];  zs[i]     = z0[i] * s0[i];
            s [i + 4] = s1[i];  zs[i + 4] = z1[i] * s1[i];
        }
    }

    // W stage source (per-lane, pre-swizzled to match linear LDS read-back):
    // round r, window W = r*8+wave: dword (o_base + lane&15)*2048 + W*16 + (lane>>4)*4
    const int* wgS = wq + (size_t)o * PKW + wave * 16 + quad * 4;   // + r*128/round
    // A-frag source bytes: ((W*4+mt)*64+lane)*16 = r*32768 + wave*4096 + mt*1024 + lane*16
    const char* xfB = (const char*)xf + (size_t)wave * 4096 + (size_t)lane * 16;
    unsigned char* ringw = &sm.ring[wave][0][0];

    f32x4 acc0 = {0.f,0.f,0.f,0.f}, acc1 = acc0, acc2 = acc0, acc3 = acc0;
    s16x8 afb[4][4];   // [ring slot][mt] — every index is literal after unroll

#define ISSUE(R) do {                                                           \
        __builtin_amdgcn_global_load_lds(                                       \
            (const __attribute__((address_space(1))) int*)(wgS + (R) * 128),    \
            (__attribute__((address_space(3))) int*)(ringw + ((R) & 3) * 1024), \
            16, 0, 0);                                                          \
        const s16x8* ap_ = (const s16x8*)(xfB + (size_t)(R) * 32768);           \
        afb[(R) & 3][0] = ap_[0];                                               \
        afb[(R) & 3][1] = ap_[64];                                              \
        afb[(R) & 3][2] = ap_[128];                                             \
        afb[(R) & 3][3] = ap_[192];                                             \
    } while (0)

#define RND(R, WN, DOISS) do {                                                  \
        if (DOISS) ISSUE((R) + 3);                                              \
        __builtin_amdgcn_sched_barrier(0);                                      \
        asm volatile("s_waitcnt vmcnt(" XSTR(WN) ")");                          \
        __builtin_amdgcn_sched_barrier(0);                                      \
        i32x4 wreg = *(const i32x4*)(ringw + ((R) & 3) * 1024 + lane * 16);     \
        s16x8 bfr;                                                              \
        _Pragma("unroll")                                                       \
        for (int d = 0; d < 4; ++d) {                                           \
            unsigned dw = (unsigned)wreg[d];                                    \
            float fh = (float)((dw >> 4) & 15u);   /* k even (high nibble) */   \
            float fl = (float)(dw & 15u);          /* k odd */                  \
            bfr[2 * d]     = (short)f2bf(fmaf(fh, s[2 * d],     -zs[2 * d]));   \
            bfr[2 * d + 1] = (short)f2bf(fmaf(fl, s[2 * d + 1], -zs[2 * d + 1]));\
        }                                                                       \
        acc0 = __builtin_amdgcn_mfma_f32_16x16x32_bf16(afb[(R) & 3][0], bfr, acc0, 0, 0, 0); \
        acc1 = __builtin_amdgcn_mfma_f32_16x16x32_bf16(afb[(R) & 3][1], bfr, acc1, 0, 0, 0); \
        acc2 = __builtin_amdgcn_mfma_f32_16x16x32_bf16(afb[(R) & 3][2], bfr, acc2, 0, 0, 0); \
        acc3 = __builtin_amdgcn_mfma_f32_16x16x32_bf16(afb[(R) & 3][3], bfr, acc3, 0, 0, 0); \
        __builtin_amdgcn_sched_barrier(0);                                      \
    } while (0)

    // prologue: blocks 0,1,2 (walled so the in-order op count stays exact)
    ISSUE(0); __builtin_amdgcn_sched_barrier(0);
    ISSUE(1); __builtin_amdgcn_sched_barrier(0);
    ISSUE(2); __builtin_amdgcn_sched_barrier(0);

    RND( 0, 15, 1);  RND( 1, 15, 1);  RND( 2, 15, 1);  RND( 3, 15, 1);
    RND( 4, 15, 1);  RND( 5, 15, 1);  RND( 6, 15, 1);  RND( 7, 15, 1);
    RND( 8, 15, 1);  RND( 9, 15, 1);  RND(10, 15, 1);  RND(11, 15, 1);
    RND(12, 15, 1);  RND(13, 10, 0);  RND(14,  5, 0);  RND(15,  0, 0);

#undef RND
#undef ISSUE

    // epilogue: acc -> lsum (wave-private slice aliases own ring; no barrier
    // needed before the write), then cross-wave reduce + bias + store.
    {
        const int mb = quad * 4;
#define STACC(MT, A)                                                      \
        sm.lsum[wave * 1024 + ((MT) * 16 + mb + 0) * 16 + o_r] = A[0];    \
        sm.lsum[wave * 1024 + ((MT) * 16 + mb + 1) * 16 + o_r] = A[1];    \
        sm.lsum[wave * 1024 + ((MT) * 16 + mb + 2) * 16 + o_r] = A[2];    \
        sm.lsum[wave * 1024 + ((MT) * 16 + mb + 3) * 16 + o_r] = A[3];
        STACC(0, acc0) STACC(1, acc1) STACC(2, acc2) STACC(3, acc3)
#undef STACC
    }
    __syncthreads();
    #pragma unroll
    for (int p = 0; p < 2; ++p) {
        int e = p * 512 + t;
        int m = e >> 4, col = e & 15;
        float v = sm.lsum[e]        + sm.lsum[1024 + e] + sm.lsum[2048 + e] + sm.lsum[3072 + e]
                + sm.lsum[4096 + e] + sm.lsum[5120 + e] + sm.lsum[6144 + e] + sm.lsum[7168 + e]
                + bias[o_base + col];
        out[(size_t)m * OUT_F + o_base + col] = v;
    }
}

extern "C" void kernel_launch(void* const* d_in, const int* in_sizes, int n_in,
                              void* d_out, int out_size, void* d_ws, size_t ws_size,
                              hipStream_t stream) {
    const float* x     = (const float*)d_in[0];
    const int*   wq    = (const int*)d_in[1];
    const float* scale = (const float*)d_in[2];
    const float* zpv   = (const float*)d_in[3];
    const float* bias  = (const float*)d_in[4];
    float* out = (float*)d_out;
    unsigned short* xf = (unsigned short*)d_ws;   // 512 KB A-fragment buffer

    prep_xfrag<<<128, 256, 0, stream>>>(x, xf);
    qlin_main<<<OUT_F / 16, 512, 0, stream>>>(wq, scale, zpv, bias, xf, out);
}

// Round 5
// 166.844 us; speedup vs baseline: 1.2148x; 1.2148x over previous
//
#include <hip/hip_runtime.h>

#define OUT_F 11008
#define IN_F  4096
#define PKW   2048   // int32 words per weight row (each word = 1 byte = 2 nibbles)
#define BLKQ  128

typedef __attribute__((ext_vector_type(8))) short          s16x8;
typedef __attribute__((ext_vector_type(8))) unsigned short u16x8;
typedef __attribute__((ext_vector_type(4))) float          f32x4;
typedef __attribute__((ext_vector_type(4))) int            i32x4;

#define AS1 __attribute__((address_space(1)))
#define AS3 __attribute__((address_space(3)))

__device__ __forceinline__ unsigned short f2bf(float f) {
    union { float f; unsigned u; } v; v.f = f;
    unsigned r = v.u + 0x8000u + ((v.u >> 16) & 1u);   // RNE-ish
    return (unsigned short)(r >> 16);
}

// Pre-swizzle x (64x4096 f32) into MFMA A-fragment order (bf16):
//   xf[((kb*4 + mt)*64 + lane)*8 + i] = x[mt*16 + (lane&15)][kb*32 + (lane>>4)*8 + i]
__global__ void prep_xfrag(const float* __restrict__ x, unsigned short* __restrict__ xf) {
    int kb   = blockIdx.x;            // 0..127 (k-window of 32)
    int t    = threadIdx.x;           // 0..255
    int mt   = t >> 6;
    int lane = t & 63;
    int m  = mt * 16 + (lane & 15);
    int k0 = kb * 32 + (lane >> 4) * 8;
    const float* xp = x + m * IN_F + k0;
    f32x4 a = *(const f32x4*)(xp);
    f32x4 b = *(const f32x4*)(xp + 4);
    u16x8 v;
    v[0] = f2bf(a[0]); v[1] = f2bf(a[1]); v[2] = f2bf(a[2]); v[3] = f2bf(a[3]);
    v[4] = f2bf(b[0]); v[5] = f2bf(b[1]); v[6] = f2bf(b[2]); v[7] = f2bf(b[3]);
    *(u16x8*)(xf + (size_t)((kb * 4 + mt) * 64 + lane) * 8) = v;
}

// LDS: 4 waves x 4-slot ring x 5 KB (1 KB W + 4x1 KB A-frags) = 80 KB,
// aliased (behind a __syncthreads) with the 16 KB epilogue reduce buffer.
union SmT {
    unsigned char ring[4][4][5120];
    float         lsum[4096];
};

// Main: one WG (256 thr = 4 waves) per 16 output cols.
// Wave w owns windows {4t + w : t=0..31}; window mod 4 == w is FIXED, so the
// dequant table is 16 VGPRs.  ALL pipeline state lives in LDS, maintained by
// global_load_lds (side-effecting: cannot be sunk/demoted/spilled, zero VGPR
// while in flight) — after R1 (demotion), R3 (load sinking) and R4 (spill,
// 75 MB scratch traffic), register pipelines are proven compiler-hostile.
// Per step: issue block t+3 (uniform 5 ops: 1 W-chunk + 4 A-frag chunks into
// the wave-private ring slot) -> sched_barrier -> s_waitcnt vmcnt(15)
// (3 blocks x 5 ops allowed in flight; uniform distance so the in-order
// counter never forces a recent op) -> ds_read W + A -> dequant -> 4 MFMA.
// No barriers in the main loop (rings are wave-private).
__global__ __launch_bounds__(256) void qlin_main(
    const int*   __restrict__ wq,
    const float* __restrict__ scale,
    const float* __restrict__ zp,
    const float* __restrict__ bias,
    const unsigned short* __restrict__ xf,
    float* __restrict__ out)
{
    __shared__ SmT sm;

    const int t      = threadIdx.x;
    const int o_base = blockIdx.x * 16;
    const int wave   = t >> 6;        // 0..3 == phase (window mod 4)
    const int lane   = t & 63;
    const int o_r    = lane & 15;     // output col within tile (B-frag col)
    const int quad   = lane >> 4;     // k-quad within 32-k window
    const int o      = o_base + o_r;

    // dequant constants for FIXED j = wave*32 + quad*8 + i, i=0..7
    float s[8], zs[8];
    {
        const float* sp  = scale + (size_t)o * BLKQ + wave * 32 + quad * 8;
        const float* zpp = zp    + (size_t)o * BLKQ + wave * 32 + quad * 8;
        f32x4 s0 = *(const f32x4*)(sp);
        f32x4 s1 = *(const f32x4*)(sp + 4);
        f32x4 z0 = *(const f32x4*)(zpp);
        f32x4 z1 = *(const f32x4*)(zpp + 4);
        #pragma unroll
        for (int i = 0; i < 4; ++i) {
            s [i]     = s0[i];  zs[i]     = z0[i] * s0[i];
            s [i + 4] = s1[i];  zs[i + 4] = z1[i] * s1[i];
        }
    }

    // step T -> window W = 4T + wave.
    // W dwords: o*2048 + W*16 + quad*4  (per-lane src; LDS dest linear lane*16)
    const int* wgS = wq + (size_t)o * PKW + wave * 16 + quad * 4;     // +T*64
    // A-frag src bytes: ((W*4+mt)*64+lane)*16 = T*16384 + wave*4096 + mt*1024 + lane*16
    const char* xfB = (const char*)xf + (size_t)(wave * 4096 + lane * 16);
    unsigned char* ringw = &sm.ring[wave][0][0];

    f32x4 acc0 = {0.f,0.f,0.f,0.f}, acc1 = acc0, acc2 = acc0, acc3 = acc0;

#define GLL(SRC, DST) __builtin_amdgcn_global_load_lds(                         \
        (const AS1 int*)(SRC), (AS3 int*)(DST), 16, 0, 0)

#define ISSUE(T) do {                                                           \
        unsigned char* dst_ = ringw + ((T) & 3) * 5120;                         \
        const char*    as_  = xfB + (size_t)(T) * 16384;                        \
        GLL(wgS + (T) * 64, dst_);                                              \
        GLL(as_,            dst_ + 1024);                                       \
        GLL(as_ + 1024,     dst_ + 2048);                                       \
        GLL(as_ + 2048,     dst_ + 3072);                                       \
        GLL(as_ + 3072,     dst_ + 4096);                                       \
    } while (0)

#define WAIT(N) do {                                                            \
        __builtin_amdgcn_sched_barrier(0);                                      \
        asm volatile("s_waitcnt vmcnt(" #N ")");                                \
        __builtin_amdgcn_sched_barrier(0);                                      \
    } while (0)

#define COMPUTE(T) do {                                                         \
        const unsigned char* slot_ = ringw + ((T) & 3) * 5120 + lane * 16;      \
        i32x4 wreg = *(const i32x4*)(slot_);                                    \
        s16x8 a0 = *(const s16x8*)(slot_ + 1024);                               \
        s16x8 a1 = *(const s16x8*)(slot_ + 2048);                               \
        s16x8 a2 = *(const s16x8*)(slot_ + 3072);                               \
        s16x8 a3 = *(const s16x8*)(slot_ + 4096);                               \
        s16x8 bfr;                                                              \
        _Pragma("unroll")                                                       \
        for (int d = 0; d < 4; ++d) {                                           \
            unsigned dw = (unsigned)wreg[d];                                    \
            float fh = (float)((dw >> 4) & 15u);   /* k even (high nibble) */   \
            float fl = (float)(dw & 15u);          /* k odd */                  \
            bfr[2 * d]     = (short)f2bf(fmaf(fh, s[2 * d],     -zs[2 * d]));   \
            bfr[2 * d + 1] = (short)f2bf(fmaf(fl, s[2 * d + 1], -zs[2 * d + 1]));\
        }                                                                       \
        acc0 = __builtin_amdgcn_mfma_f32_16x16x32_bf16(a0, bfr, acc0, 0, 0, 0); \
        acc1 = __builtin_amdgcn_mfma_f32_16x16x32_bf16(a1, bfr, acc1, 0, 0, 0); \
        acc2 = __builtin_amdgcn_mfma_f32_16x16x32_bf16(a2, bfr, acc2, 0, 0, 0); \
        acc3 = __builtin_amdgcn_mfma_f32_16x16x32_bf16(a3, bfr, acc3, 0, 0, 0); \
    } while (0)

    // prologue: 3 blocks in flight (15 VMEM ops)
    ISSUE(0); __builtin_amdgcn_sched_barrier(0);
    ISSUE(1); __builtin_amdgcn_sched_barrier(0);
    ISSUE(2); __builtin_amdgcn_sched_barrier(0);

    for (int T = 0; T < 29; ++T) {
        ISSUE(T + 3);
        WAIT(15);
        COMPUTE(T);
        __builtin_amdgcn_sched_barrier(0);
    }
    WAIT(10); COMPUTE(29);
    WAIT(5);  COMPUTE(30);
    WAIT(0);  COMPUTE(31);

#undef COMPUTE
#undef WAIT
#undef ISSUE
#undef GLL

    // rings dead from here; lsum aliases them -> barrier BEFORE the writes
    __syncthreads();
    {
        const int mb = quad * 4;
#define STACC(MT, A)                                                      \
        sm.lsum[wave * 1024 + ((MT) * 16 + mb + 0) * 16 + o_r] = A[0];    \
        sm.lsum[wave * 1024 + ((MT) * 16 + mb + 1) * 16 + o_r] = A[1];    \
        sm.lsum[wave * 1024 + ((MT) * 16 + mb + 2) * 16 + o_r] = A[2];    \
        sm.lsum[wave * 1024 + ((MT) * 16 + mb + 3) * 16 + o_r] = A[3];
        STACC(0, acc0) STACC(1, acc1) STACC(2, acc2) STACC(3, acc3)
#undef STACC
    }
    __syncthreads();
    #pragma unroll
    for (int p = 0; p < 4; ++p) {
        int e = p * 256 + t;
        int m = e >> 4, col = e & 15;
        float v = sm.lsum[e] + sm.lsum[1024 + e] + sm.lsum[2048 + e] + sm.lsum[3072 + e]
                + bias[o_base + col];
        out[(size_t)m * OUT_F + o_base + col] = v;
    }
}

extern "C" void kernel_launch(void* const* d_in, const int* in_sizes, int n_in,
                              void* d_out, int out_size, void* d_ws, size_t ws_size,
                              hipStream_t stream) {
    const float* x     = (const float*)d_in[0];
    const int*   wq    = (const int*)d_in[1];
    const float* scale = (const float*)d_in[2];
    const float* zpv   = (const float*)d_in[3];
    const float* bias  = (const float*)d_in[4];
    float* out = (float*)d_out;
    unsigned short* xf = (unsigned short*)d_ws;   // 512 KB A-fragment buffer

    prep_xfrag<<<128, 256, 0, stream>>>(x, xf);
    qlin_main<<<OUT_F / 16, 256, 0, stream>>>(wq, scale, zpv, bias, xf, out);
}

// Round 9
// 166.369 us; speedup vs baseline: 1.2183x; 1.0029x over previous
//
#include <hip/hip_runtime.h>

#define OUT_F 11008
#define IN_F  4096
#define PKW   2048   // int32 words per weight row (each word = 1 byte = 2 nibbles)
#define BLKQ  128
#define NTILE 172    // 11008 / 64 output tiles
#define XFOFF (512 * 1024)

typedef __attribute__((ext_vector_type(8))) short          s16x8;
typedef __attribute__((ext_vector_type(8))) unsigned short u16x8;
typedef __attribute__((ext_vector_type(4))) float          f32x4;
typedef __attribute__((ext_vector_type(4))) int            i32x4;

__device__ __forceinline__ unsigned short f2bf(float f) {
    union { float f; unsigned u; } v; v.f = f;
    unsigned r = v.u + 0x8000u + ((v.u >> 16) & 1u);   // RNE-ish
    return (unsigned short)(r >> 16);
}

// Pre-swizzle x (64x4096 f32) into MFMA A-fragment order (bf16):
//   xf[((kb*4 + mt)*64 + lane)*8 + i] = x[mt*16 + (lane&15)][kb*32 + (lane>>4)*8 + i]
__global__ void prep_xfrag(const float* __restrict__ x, unsigned short* __restrict__ xf) {
    int kb   = blockIdx.x;            // 0..127 (k-window of 32)
    int t    = threadIdx.x;           // 0..255
    int mt   = t >> 6;
    int lane = t & 63;
    int m  = mt * 16 + (lane & 15);
    int k0 = kb * 32 + (lane >> 4) * 8;
    const float* xp = x + m * IN_F + k0;
    f32x4 a = *(const f32x4*)(xp);
    f32x4 b = *(const f32x4*)(xp + 4);
    u16x8 v;
    v[0] = f2bf(a[0]); v[1] = f2bf(a[1]); v[2] = f2bf(a[2]); v[3] = f2bf(a[3]);
    v[4] = f2bf(b[0]); v[5] = f2bf(b[1]); v[6] = f2bf(b[2]); v[7] = f2bf(b[3]);
    *(u16x8*)(xf + (size_t)((kb * 4 + mt) * 64 + lane) * 8) = v;
}

// Main: 688 blocks = (tile = bid>>2: 64 output cols, kq = bid&3: K-quarter).
// MINIMAL delta from the R0 PASSING kernel: waves split COLUMNS (wave w owns
// cols w*16..+16) instead of K, so the dequanted 64x128 bf16 tile and the
// global A-fragment reads are shared/reused 4x (A traffic 352 -> 88 MB, and
// xf is 512 KB = L2-resident). Staging pattern, dequant math, barrier
// structure, register weight-prefetch, and B-frag LDS reads are R0 verbatim
// (thread t stages 16 dwords of row t>>2, j-group t&3; s[32]/zs[32]
// unchanged). No gll, no inline asm, no register pipeline, no cross-wave
// reduction (waves own disjoint cols -> direct K-quarter partial store).
__global__ __launch_bounds__(256) void qlin_main(
    const int*   __restrict__ wq,
    const float* __restrict__ scale,
    const float* __restrict__ zp,
    const unsigned short* __restrict__ xf,
    float* __restrict__ part)
{
    // 64 rows x 136 bf16 (pad 8) = 17408 B
    __shared__ __align__(16) unsigned short smem[64 * 136];

    const int t      = threadIdx.x;
    const int tile   = blockIdx.x >> 2;
    const int kq     = blockIdx.x & 3;      // K-quarter (k = kq*1024 ..+1024)
    const int o_base = tile * 64;
    const int wave   = t >> 6;              // col-slice 0..3
    const int lane   = t & 63;
    const int quad   = lane >> 4;

    // staging decomposition (R0 verbatim, rows extended 16->64):
    // thread stages 16 dwords (32 j) of one row
    const int d     = t & 3;                // j-group: j in [d*32, d*32+32)
    const int row_r = t >> 2;               // staged row 0..63

    // per-thread dequant constants: s[j], zp*s[j], j = d*32 + i (j = k mod 128)
    float s[32], zs[32];
    {
        const float* sp  = scale + (size_t)(o_base + row_r) * BLKQ + d * 32;
        const float* zpp = zp    + (size_t)(o_base + row_r) * BLKQ + d * 32;
        #pragma unroll
        for (int i = 0; i < 8; ++i) {
            f32x4 sv = *(const f32x4*)(sp  + i * 4);
            f32x4 zv = *(const f32x4*)(zpp + i * 4);
            #pragma unroll
            for (int c = 0; c < 4; ++c) {
                s [i * 4 + c] = sv[c];
                zs[i * 4 + c] = zv[c] * sv[c];
            }
        }
    }

    // global staging base (dword index); each round advances by 64 dwords (128 k)
    const int* wbase = wq + (size_t)(o_base + row_r) * PKW + kq * 512 + d * 16;
    unsigned short* myw = smem + row_r * 136 + d * 32;

    f32x4 acc[4];
    #pragma unroll
    for (int mt = 0; mt < 4; ++mt) acc[mt] = (f32x4){0.f, 0.f, 0.f, 0.f};

    i32x4 wreg[4];
    #pragma unroll
    for (int q = 0; q < 4; ++q) wreg[q] = *(const i32x4*)(wbase + q * 4);

    const s16x8* xfv = (const s16x8*)xf;
    // B-frag read base: LDS row = this wave's col (wave*16 + lane&15)
    const unsigned short* bbase = smem + (wave * 16 + (lane & 15)) * 136;

    for (int tt = 0; tt < 8; ++tt) {
        __syncthreads();   // previous round's LDS reads complete

        // dequant 16 dwords -> 32 bf16, write 4x16B to LDS (R0 verbatim)
        #pragma unroll
        for (int q = 0; q < 4; ++q) {
            u16x8 ob;
            #pragma unroll
            for (int pp = 0; pp < 4; ++pp) {
                unsigned dw = (unsigned)wreg[q][pp];
                int p = q * 4 + pp;                  // local dword 0..15
                float fh = (float)((dw >> 4) & 15u); // k = even (high nibble first)
                float fl = (float)(dw & 15u);
                ob[2 * pp]     = f2bf(fmaf(fh, s[2 * p],     -zs[2 * p]));
                ob[2 * pp + 1] = f2bf(fmaf(fl, s[2 * p + 1], -zs[2 * p + 1]));
            }
            *(u16x8*)(myw + q * 8) = ob;
        }

        // prefetch next round's packed weights (R0 verbatim)
        if (tt < 7) {
            const int* nb = wbase + (tt + 1) * 64;
            #pragma unroll
            for (int q = 0; q < 4; ++q) wreg[q] = *(const i32x4*)(nb + q * 4);
        }

        __syncthreads();   // tile visible

        #pragma unroll
        for (int q0 = 0; q0 < 4; ++q0) {
            s16x8 bfrag = *(const s16x8*)(bbase + q0 * 32 + quad * 8);
            int kb = kq * 32 + tt * 4 + q0;          // global k-window
            #pragma unroll
            for (int mt = 0; mt < 4; ++mt) {
                s16x8 afrag = xfv[(size_t)(kb * 4 + mt) * 64 + lane];
                acc[mt] = __builtin_amdgcn_mfma_f32_16x16x32_bf16(afrag, bfrag, acc[mt], 0, 0, 0);
            }
        }
    }

    // direct K-quarter partial store: C/D col=lane&15 -> oc, row=quad*4+reg -> m
    const int oc = o_base + wave * 16 + (lane & 15);
    float* pp = part + (size_t)kq * (64 * OUT_F) + oc;
    #pragma unroll
    for (int mt = 0; mt < 4; ++mt) {
        #pragma unroll
        for (int r = 0; r < 4; ++r) {
            pp[(size_t)(mt * 16 + quad * 4 + r) * OUT_F] = acc[mt][r];
        }
    }
}

// out[m][o] = sum of 4 K-quarter partials + bias[o]; 688*256 threads,
// one f32x4 each (64*11008/4 = 176128 exactly). Same associativity as R0's
// reduction (((q0+q1)+q2)+q3, bias last) -> bit-identical output expected.
__global__ __launch_bounds__(256) void combine(
    const float* __restrict__ part, const float* __restrict__ bias,
    float* __restrict__ out)
{
    int i = blockIdx.x * 256 + threadIdx.x;          // vec4 index
    const f32x4* p = (const f32x4*)part;
    f32x4 v = p[i];
    v += p[176128 + i];
    v += p[2 * 176128 + i];
    v += p[3 * 176128 + i];
    f32x4 b = ((const f32x4*)bias)[i % 2752];        // o/4 = i mod (11008/4)
    ((f32x4*)out)[i] = v + b;
}

extern "C" void kernel_launch(void* const* d_in, const int* in_sizes, int n_in,
                              void* d_out, int out_size, void* d_ws, size_t ws_size,
                              hipStream_t stream) {
    const float* x     = (const float*)d_in[0];
    const int*   wq    = (const int*)d_in[1];
    const float* scale = (const float*)d_in[2];
    const float* zpv   = (const float*)d_in[3];
    const float* bias  = (const float*)d_in[4];
    float* out = (float*)d_out;
    unsigned short* xf = (unsigned short*)d_ws;                 // 512 KB A-frags
    float* part = (float*)((char*)d_ws + XFOFF);                // 4 x 64 x 11008 f32

    prep_xfrag<<<128, 256, 0, stream>>>(x, xf);
    qlin_main<<<NTILE * 4, 256, 0, stream>>>(wq, scale, zpv, xf, part);
    combine<<<688, 256, 0, stream>>>(part, bias, out);
}

// Round 10
// 164.027 us; speedup vs baseline: 1.2357x; 1.0143x over previous
//
#include <hip/hip_runtime.h>

#define OUT_F 11008
#define IN_F  4096
#define PKW   2048   // int32 words per weight row (each word = 1 byte = 2 nibbles)
#define BLKQ  128
#define NTILE 172    // 11008 / 64 output tiles
#define XFOFF (512 * 1024)

typedef __attribute__((ext_vector_type(8))) short          s16x8;
typedef __attribute__((ext_vector_type(8))) unsigned short u16x8;
typedef __attribute__((ext_vector_type(4))) float          f32x4;
typedef __attribute__((ext_vector_type(4))) int            i32x4;

__device__ __forceinline__ unsigned short f2bf(float f) {
    union { float f; unsigned u; } v; v.f = f;
    unsigned r = v.u + 0x8000u + ((v.u >> 16) & 1u);   // RNE-ish
    return (unsigned short)(r >> 16);
}

// Pre-swizzle x (64x4096 f32) into MFMA A-fragment order (bf16):
//   xf[((kb*4 + mt)*64 + lane)*8 + i] = x[mt*16 + (lane&15)][kb*32 + (lane>>4)*8 + i]
__global__ void prep_xfrag(const float* __restrict__ x, unsigned short* __restrict__ xf) {
    int kb   = blockIdx.x;            // 0..127 (k-window of 32)
    int t    = threadIdx.x;           // 0..255
    int mt   = t >> 6;
    int lane = t & 63;
    int m  = mt * 16 + (lane & 15);
    int k0 = kb * 32 + (lane >> 4) * 8;
    const float* xp = x + m * IN_F + k0;
    f32x4 a = *(const f32x4*)(xp);
    f32x4 b = *(const f32x4*)(xp + 4);
    u16x8 v;
    v[0] = f2bf(a[0]); v[1] = f2bf(a[1]); v[2] = f2bf(a[2]); v[3] = f2bf(a[3]);
    v[4] = f2bf(b[0]); v[5] = f2bf(b[1]); v[6] = f2bf(b[2]); v[7] = f2bf(b[3]);
    *(u16x8*)(xf + (size_t)((kb * 4 + mt) * 64 + lane) * 8) = v;
}

// Main: 688 blocks = (tile = bid>>2: 64 output cols, kq = bid&3: K-quarter).
// Delta from R9 (PASSING, 53.8 µs, VGPR=72):
//  (1) __launch_bounds__(256, 3): R9's VGPR_Count=72 < the 64-reg s/zs table
//      proves the compiler rematerialized the dequant constants by re-loading
//      scale/zp from global EVERY ROUND (no scratch traffic, so remat not
//      spill) — a serial L2 dependent chain inside each dequant phase. Cap
//      at 3 waves/SIMD (168 VGPR) keeps the table resident; grid needs only
//      2.69 WGs/CU, so 3 WGs/CU co-residency is preserved.
//  (2) A-fragments staged to LDS once per WG per round (each thread copies
//      4x16 B, coalesced, issued at the top of the dequant phase so the L2
//      latency hides under dequant VALU). R9's counters showed the 4 waves
//      redundantly loading the SAME afrags from global: 352 MB of L2 reads.
//      Now 88 MB, and the MFMA phase reads LDS only.
// Math is bit-identical to R9 -> absmax 0.0625 expected unchanged.
__global__ __launch_bounds__(256, 3) void qlin_main(
    const int*   __restrict__ wq,
    const float* __restrict__ scale,
    const float* __restrict__ zp,
    const unsigned short* __restrict__ xf,
    float* __restrict__ part)
{
    // B tile: 64 rows x 136 bf16 (pad 8) = 17408 B
    __shared__ __align__(16) unsigned short smem[64 * 136];
    // A frags for the round's 4 windows: 4 x 4 x 64 x 16 B = 16384 B
    __shared__ __align__(16) unsigned char afb[16384];

    const int t      = threadIdx.x;
    const int tile   = blockIdx.x >> 2;
    const int kq     = blockIdx.x & 3;      // K-quarter (k = kq*1024 ..+1024)
    const int o_base = tile * 64;
    const int wave   = t >> 6;              // col-slice 0..3
    const int lane   = t & 63;
    const int quad   = lane >> 4;

    // staging decomposition (R0/R9 verbatim): thread stages 16 dwords (32 j)
    const int d     = t & 3;                // j-group: j in [d*32, d*32+32)
    const int row_r = t >> 2;               // staged row 0..63

    // per-thread dequant constants: s[j], zp*s[j], j = d*32 + i (j = k mod 128)
    float s[32], zs[32];
    {
        const float* sp  = scale + (size_t)(o_base + row_r) * BLKQ + d * 32;
        const float* zpp = zp    + (size_t)(o_base + row_r) * BLKQ + d * 32;
        #pragma unroll
        for (int i = 0; i < 8; ++i) {
            f32x4 sv = *(const f32x4*)(sp  + i * 4);
            f32x4 zv = *(const f32x4*)(zpp + i * 4);
            #pragma unroll
            for (int c = 0; c < 4; ++c) {
                s [i * 4 + c] = sv[c];
                zs[i * 4 + c] = zv[c] * sv[c];
            }
        }
    }

    // global staging base (dword index); each round advances by 64 dwords (128 k)
    const int* wbase = wq + (size_t)(o_base + row_r) * PKW + kq * 512 + d * 16;
    unsigned short* myw = smem + row_r * 136 + d * 32;

    f32x4 acc[4];
    #pragma unroll
    for (int mt = 0; mt < 4; ++mt) acc[mt] = (f32x4){0.f, 0.f, 0.f, 0.f};

    i32x4 wreg[4];
    #pragma unroll
    for (int q = 0; q < 4; ++q) wreg[q] = *(const i32x4*)(wbase + q * 4);

    // A-frag copy source for round tt: xf bytes [(kq*32+tt*4)*4096, +16384)
    // thread t copies chunks c = i*256 + t (16 B each), linear -> coalesced.
    const char* xfbase = (const char*)xf + (size_t)(kq * 32) * 4096 + t * 16;
    // B-frag read base: LDS row = this wave's col (wave*16 + lane&15)
    const unsigned short* bbase = smem + (wave * 16 + (lane & 15)) * 136;

    for (int tt = 0; tt < 8; ++tt) {
        __syncthreads();   // previous round's LDS reads complete

        // A-frag stage: issue the 4 global loads FIRST (L2 latency hides
        // under the dequant VALU below), LDS writes after.
        const char* asrc = xfbase + (size_t)tt * 16384;
        u16x8 av0 = *(const u16x8*)(asrc);
        u16x8 av1 = *(const u16x8*)(asrc + 4096);
        u16x8 av2 = *(const u16x8*)(asrc + 8192);
        u16x8 av3 = *(const u16x8*)(asrc + 12288);

        // dequant 16 dwords -> 32 bf16, write 4x16B to LDS (R9 verbatim)
        #pragma unroll
        for (int q = 0; q < 4; ++q) {
            u16x8 ob;
            #pragma unroll
            for (int pp = 0; pp < 4; ++pp) {
                unsigned dw = (unsigned)wreg[q][pp];
                int p = q * 4 + pp;                  // local dword 0..15
                float fh = (float)((dw >> 4) & 15u); // k = even (high nibble first)
                float fl = (float)(dw & 15u);
                ob[2 * pp]     = f2bf(fmaf(fh, s[2 * p],     -zs[2 * p]));
                ob[2 * pp + 1] = f2bf(fmaf(fl, s[2 * p + 1], -zs[2 * p + 1]));
            }
            *(u16x8*)(myw + q * 8) = ob;
        }

        // A-frag LDS writes (linear chunk c*16, c = i*256 + t)
        *(u16x8*)(afb + t * 16)         = av0;
        *(u16x8*)(afb + t * 16 + 4096)  = av1;
        *(u16x8*)(afb + t * 16 + 8192)  = av2;
        *(u16x8*)(afb + t * 16 + 12288) = av3;

        // prefetch next round's packed weights (R9 verbatim)
        if (tt < 7) {
            const int* nb = wbase + (tt + 1) * 64;
            #pragma unroll
            for (int q = 0; q < 4; ++q) wreg[q] = *(const i32x4*)(nb + q * 4);
        }

        __syncthreads();   // tile + afrags visible

        #pragma unroll
        for (int q0 = 0; q0 < 4; ++q0) {
            s16x8 bfrag = *(const s16x8*)(bbase + q0 * 32 + quad * 8);
            #pragma unroll
            for (int mt = 0; mt < 4; ++mt) {
                s16x8 afrag = *(const s16x8*)(afb + ((q0 * 4 + mt) * 64 + lane) * 16);
                acc[mt] = __builtin_amdgcn_mfma_f32_16x16x32_bf16(afrag, bfrag, acc[mt], 0, 0, 0);
            }
        }
    }

    // direct K-quarter partial store: C/D col=lane&15 -> oc, row=quad*4+reg -> m
    const int oc = o_base + wave * 16 + (lane & 15);
    float* pp = part + (size_t)kq * (64 * OUT_F) + oc;
    #pragma unroll
    for (int mt = 0; mt < 4; ++mt) {
        #pragma unroll
        for (int r = 0; r < 4; ++r) {
            pp[(size_t)(mt * 16 + quad * 4 + r) * OUT_F] = acc[mt][r];
        }
    }
}

// out[m][o] = sum of 4 K-quarter partials + bias[o]; 688*256 threads,
// one f32x4 each (64*11008/4 = 176128 exactly). Same associativity as R0's
// reduction (((q0+q1)+q2)+q3, bias last).
__global__ __launch_bounds__(256) void combine(
    const float* __restrict__ part, const float* __restrict__ bias,
    float* __restrict__ out)
{
    int i = blockIdx.x * 256 + threadIdx.x;          // vec4 index
    const f32x4* p = (const f32x4*)part;
    f32x4 v = p[i];
    v += p[176128 + i];
    v += p[2 * 176128 + i];
    v += p[3 * 176128 + i];
    f32x4 b = ((const f32x4*)bias)[i % 2752];        // o/4 = i mod (11008/4)
    ((f32x4*)out)[i] = v + b;
}

extern "C" void kernel_launch(void* const* d_in, const int* in_sizes, int n_in,
                              void* d_out, int out_size, void* d_ws, size_t ws_size,
                              hipStream_t stream) {
    const float* x     = (const float*)d_in[0];
    const int*   wq    = (const int*)d_in[1];
    const float* scale = (const float*)d_in[2];
    const float* zpv   = (const float*)d_in[3];
    const float* bias  = (const float*)d_in[4];
    float* out = (float*)d_out;
    unsigned short* xf = (unsigned short*)d_ws;                 // 512 KB A-frags
    float* part = (float*)((char*)d_ws + XFOFF);                // 4 x 64 x 11008 f32

    prep_xfrag<<<128, 256, 0, stream>>>(x, xf);
    qlin_main<<<NTILE * 4, 256, 0, stream>>>(wq, scale, zpv, xf, part);
    combine<<<688, 256, 0, stream>>>(part, bias, out);
}